// Round 3
// baseline (310.873 us; speedup 1.0000x reference)
//
#include <hip/hip_runtime.h>
#include <math.h>

// ---------------------------------------------------------------------------
// MutilLocalLoss on MI355X.
// Level constants (derived to match Python int()/round() semantics exactly):
//   lev: C,  A,  CROP, TOP, OH(=OW), NSJ, NS,   SPLITS, BPB, EBASE,  ENTRY_START
//   0:   64, 16,  6,    5,  11,      3,   33,   1,      1,   0,      0
//   1:   32, 32, 13,   10,  20,      5,  100,   2,      2,   968,    968
//   2:   16, 64, 26,   19,  39,     10,  390,   4,      7,   7368,   4168
//   3:    8,128, 53,   38,  76,     19, 1444,   8,     23,  56040,  16336
// ws layout (floats): [0,32) = sc per (lev,b); [32, 32+425704) = corr partials.
// ---------------------------------------------------------------------------

#define WS_SC 0
#define WS_CORR 32

__device__ __forceinline__ float block_sum256(float v, float* sw) {
#pragma unroll
  for (int o = 32; o > 0; o >>= 1) v += __shfl_down(v, o, 64);
  if ((threadIdx.x & 63) == 0) sw[threadIdx.x >> 6] = v;
  __syncthreads();
  float r = (threadIdx.x < 4) ? sw[threadIdx.x] : 0.0f;
  r += __shfl_down(r, 2, 64);
  r += __shfl_down(r, 1, 64);
  __syncthreads();
  return r;  // total valid in thread 0
}

// ---------------- prep: per-(lev,b) scale factors ---------------------------
template <int C, int A, int CROP, int TOP>
__device__ void prep_level(const float* __restrict__ grd,
                           const float* __restrict__ sat,
                           const float* __restrict__ mask, int b,
                           float* __restrict__ sc_out, float* sw) {
  const float* gb = grd + (size_t)b * C * A * A;
  const float* sb = sat + (size_t)b * C * A * A;
  float s1 = 0.0f;
  constexpr int N1 = C * CROP * CROP;
  for (int idx = threadIdx.x; idx < N1; idx += 256) {
    int c = idx / (CROP * CROP);
    int r = idx - c * (CROP * CROP);
    int h = r / CROP;
    int w = r - h * CROP;
    float m = mask[(TOP + h) * A + (TOP + w)];
    float g = gb[((size_t)c * A + (TOP + h)) * A + (TOP + w)] * m;
    s1 += g * g;
  }
  s1 = block_sum256(s1, sw);
  float s2 = 0.0f;
  constexpr int N2 = C * A * A;
  for (int idx = threadIdx.x; idx < N2; idx += 256) {
    int hw = idx & (A * A - 1);  // A*A is a power of two
    float vv = sb[idx];
    s2 += vv * vv * mask[hw];
  }
  s2 = block_sum256(s2, sw);
  if (threadIdx.x == 0) {
    float norm = sqrtf(s1);
    float denom = fmaxf(sqrtf(s2 + 1e-8f), 1e-6f);
    *sc_out = 2.0f / (fmaxf(norm, 1e-12f) * denom);
  }
}

__global__ __launch_bounds__(256) void prep_kernel(
    const float* g0, const float* s0, const float* m0, const float* g1,
    const float* s1, const float* m1, const float* g2, const float* s2,
    const float* m2, const float* g3, const float* s3, const float* m3,
    float* ws, float* out) {
  __shared__ float sw[4];
  if (blockIdx.x == 0 && threadIdx.x == 0) out[0] = 0.0f;
  int lev = blockIdx.x >> 3;
  int b = blockIdx.x & 7;
  float* sc = ws + WS_SC + lev * 8 + b;
  if (lev == 0)      prep_level<64, 16, 6, 5>(g0, s0, m0, b, sc, sw);
  else if (lev == 1) prep_level<32, 32, 13, 10>(g1, s1, m1, b, sc, sw);
  else if (lev == 2) prep_level<16, 64, 26, 19>(g2, s2, m2, b, sc, sw);
  else               prep_level<8, 128, 53, 38>(g3, s3, m3, b, sc, sw);
}

// ---------------- corr: raw correlation partials ----------------------------
// Per-thread 4-wide sliding window: 4 FMA per 1 new sat load + 1 LDS broadcast.
template <int CROP>
__device__ __forceinline__ void dot_row(const float* __restrict__ srow,
                                        const float* __restrict__ grow,
                                        float acc[4]) {
  float r[4];
  r[0] = srow[0];
  r[1] = srow[1];
  r[2] = srow[2];
#pragma unroll
  for (int w = 0; w < CROP; ++w) {
    r[(w + 3) & 3] = srow[w + 3];  // in-bounds: j0c+CROP+2 <= A-1 by construction
    float g = grow[w];
    acc[0] = fmaf(r[(w + 0) & 3], g, acc[0]);
    acc[1] = fmaf(r[(w + 1) & 3], g, acc[1]);
    acc[2] = fmaf(r[(w + 2) & 3], g, acc[2]);
    acc[3] = fmaf(r[(w + 3) & 3], g, acc[3]);
  }
}

template <int C, int A, int CROP, int TOP, int OH, int NSJ, int SPLITS, int BPB,
          int EBASE>
__device__ void corr_level(int rel, const float* __restrict__ grd,
                           const float* __restrict__ sat,
                           const float* __restrict__ mask,
                           float* __restrict__ ws, float* g_lds) {
  constexpr int CSP = C / SPLITS;
  constexpr int NS = NSJ * OH;
  constexpr int OW = OH;
  constexpr int E = 8 * OH * OW;
  const int perb = SPLITS * BPB;
  const int b = rel / perb;
  const int r2 = rel - b * perb;
  const int split = r2 / BPB;
  const int chunk = r2 - split * BPB;
  const int c0 = split * CSP;

  // stage masked grd chunk into LDS (~11 KB for every level)
  const float* gb = grd + (size_t)(b * C + c0) * A * A;
  constexpr int GN = CSP * CROP * CROP;
  for (int idx = threadIdx.x; idx < GN; idx += 64) {
    int c = idx / (CROP * CROP);
    int r = idx - c * (CROP * CROP);
    int h = r / CROP;
    int w = r - h * CROP;
    g_lds[idx] = gb[((size_t)c * A + (TOP + h)) * A + (TOP + w)] *
                 mask[(TOP + h) * A + (TOP + w)];
  }
  __syncthreads();

  const int s = chunk * 64 + (int)threadIdx.x;
  const bool active = s < NS;
  const int ss = active ? s : 0;
  const int i = ss / NSJ;
  const int j0 = (ss - i * NSJ) * 4;
  const int j0c = min(j0, OW - 4);  // clamp: edge strips overlap, ownership below

  float acc[4] = {0.f, 0.f, 0.f, 0.f};
  const float* sb = sat + (size_t)(b * C + c0) * A * A;
#pragma unroll 1
  for (int c = 0; c < CSP; ++c) {
    const float* satc = sb + (size_t)c * A * A;
    const float* gl = g_lds + c * CROP * CROP;
#pragma unroll 1
    for (int h = 0; h < CROP; ++h) {
      dot_row<CROP>(satc + (i + h) * A + j0c, gl + h * CROP, acc);
    }
  }
  if (active) {
    float* dst = ws + WS_CORR + EBASE + split * E + (b * OH + i) * OW + j0c;
    const int own = j0 - j0c;  // first owned lane of the (possibly clamped) strip
#pragma unroll
    for (int t = 0; t < 4; ++t)
      if (t >= own) dst[t] = acc[t];
  }
}

__global__ __launch_bounds__(64) void corr_kernel(
    const float* g0, const float* s0, const float* m0, const float* g1,
    const float* s1, const float* m1, const float* g2, const float* s2,
    const float* m2, const float* g3, const float* s3, const float* m3,
    float* ws) {
  __shared__ float g_lds[2816];
  const int bid = blockIdx.x;
  if (bid < 8)
    corr_level<64, 16, 6, 5, 11, 3, 1, 1, 0>(bid, g0, s0, m0, ws, g_lds);
  else if (bid < 40)
    corr_level<32, 32, 13, 10, 20, 5, 2, 2, 968>(bid - 8, g1, s1, m1, ws, g_lds);
  else if (bid < 264)
    corr_level<16, 64, 26, 19, 39, 10, 4, 7, 7368>(bid - 40, g2, s2, m2, ws, g_lds);
  else
    corr_level<8, 128, 53, 38, 76, 19, 8, 23, 56040>(bid - 264, g3, s3, m3, ws, g_lds);
}

// ---------------- loss: softplus contrast + scalar reduction ----------------
__global__ __launch_bounds__(256) void loss_kernel(const float* __restrict__ u,
                                                   const float* __restrict__ v,
                                                   const float* __restrict__ hd,
                                                   const float* __restrict__ ws,
                                                   float* __restrict__ out) {
  __shared__ float sw[4];
  const int e = blockIdx.x * 256 + threadIdx.x;
  float term = 0.0f;
  if (e < 62544) {
    int lev, start, OH, EBASE, SPLITS;
    float mpp;
    if (e < 968)        { lev = 0; start = 0;     OH = 11; EBASE = 0;     SPLITS = 1; mpp = 6.4f; }
    else if (e < 4168)  { lev = 1; start = 968;   OH = 20; EBASE = 968;   SPLITS = 2; mpp = 3.2f; }
    else if (e < 16336) { lev = 2; start = 4168;  OH = 39; EBASE = 7368;  SPLITS = 4; mpp = 1.6f; }
    else                { lev = 3; start = 16336; OH = 76; EBASE = 56040; SPLITS = 8; mpp = 0.8f; }
    const int r = e - start;
    const int ow2 = OH * OH;
    const int b = r / ow2;
    const float scv = ws[WS_SC + lev * 8 + b];
    // gt position, replicating the reference fp32 op order
    float t = hd[b] * 10.0f;
    t = t / 180.0f;
    t = t * 3.14159265358979323846f;
    const float cs = cosf(t), sn = sinf(t);
    const float gdx = -u[b] * 20.0f;
    const float gdy = -v[b] * 20.0f;
    const float dxr = -gdx * cs + gdy * sn;
    const float dyr = gdx * sn + gdy * cs;
    int wi = (int)rintf(OH * 0.5f - 0.5f + dxr / mpp);  // rintf = round-half-even
    int hi = (int)rintf(OH * 0.5f - 0.5f + dyr / mpp);
    wi = min(max(wi, 0), OH - 1);
    hi = min(max(hi, 0), OH - 1);
    const int posoff = (b * OH + hi) * OH + wi;
    const int E = 8 * ow2;
    float raw = 0.0f, rp = 0.0f;
    const float* base = ws + WS_CORR + EBASE;
    for (int sp = 0; sp < SPLITS; ++sp) {
      raw += base[sp * E + r];
      rp += base[sp * E + posoff];
    }
    // pos - corr = sc * (raw_entry - raw_pos);  logaddexp(0, 10*(pos-corr))
    const float z = 10.0f * scv * (raw - rp);
    const float spl = fmaxf(z, 0.0f) + log1pf(expf(-fabsf(z)));
    term = spl / (8.0f * (float)(ow2 - 1));
  }
  const float tot = block_sum256(term, sw);
  if (threadIdx.x == 0) atomicAdd(out, tot);
}

// ---------------------------------------------------------------------------
extern "C" void kernel_launch(void* const* d_in, const int* in_sizes, int n_in,
                              void* d_out, int out_size, void* d_ws,
                              size_t ws_size, hipStream_t stream) {
  const float* g0 = (const float*)d_in[0];
  const float* s0 = (const float*)d_in[1];
  const float* m0 = (const float*)d_in[2];
  const float* g1 = (const float*)d_in[3];
  const float* s1 = (const float*)d_in[4];
  const float* m1 = (const float*)d_in[5];
  const float* g2 = (const float*)d_in[6];
  const float* s2 = (const float*)d_in[7];
  const float* m2 = (const float*)d_in[8];
  const float* g3 = (const float*)d_in[9];
  const float* s3 = (const float*)d_in[10];
  const float* m3 = (const float*)d_in[11];
  const float* u  = (const float*)d_in[12];
  const float* v  = (const float*)d_in[13];
  const float* hd = (const float*)d_in[14];
  float* ws = (float*)d_ws;
  float* out = (float*)d_out;

  prep_kernel<<<dim3(32), dim3(256), 0, stream>>>(g0, s0, m0, g1, s1, m1, g2,
                                                  s2, m2, g3, s3, m3, ws, out);
  corr_kernel<<<dim3(1736), dim3(64), 0, stream>>>(g0, s0, m0, g1, s1, m1, g2,
                                                   s2, m2, g3, s3, m3, ws);
  loss_kernel<<<dim3(245), dim3(256), 0, stream>>>(u, v, hd, ws, out);
}

// Round 4
// 181.285 us; speedup vs baseline: 1.7148x; 1.7148x over previous
//
#include <hip/hip_runtime.h>
#include <math.h>

// ---------------------------------------------------------------------------
// MutilLocalLoss on MI355X.
// Level constants (derived to match Python int()/round() semantics exactly):
//   lev: C,  A,  CROP, TOP, OH(=OW), NSJ, NS,   SPLITS, BPB, EBASE,  ENTRY_START
//   0:   64, 16,  6,    5,  11,      3,   33,   1,      1,   0,      0
//   1:   32, 32, 13,   10,  20,      5,  100,   2,      2,   968,    968
//   2:   16, 64, 26,   19,  39,     10,  390,   4,      7,   7368,   4168
//   3:    8,128, 53,   38,  76,     19, 1444,   8,     23,  56040,  16336
// ws layout (floats): [0,32) sc per (lev,b); [32, 32+425704) corr partials;
//                     [425736, 425736+1024) prep partial sums (32 pairs × 16 × 2).
// R3: prep was 266µs latency-bound (32 blocks, scalar loads, 0.68% occupancy).
//     Split into 512-block vectorized partial pass + tiny finalize.
// ---------------------------------------------------------------------------

#define WS_SC 0
#define WS_CORR 32
#define WS_PART (32 + 425704)

__device__ __forceinline__ float block_sum256(float v, float* sw) {
#pragma unroll
  for (int o = 32; o > 0; o >>= 1) v += __shfl_down(v, o, 64);
  if ((threadIdx.x & 63) == 0) sw[threadIdx.x >> 6] = v;
  __syncthreads();
  float r = (threadIdx.x < 4) ? sw[threadIdx.x] : 0.0f;
  r += __shfl_down(r, 2, 64);
  r += __shfl_down(r, 1, 64);
  __syncthreads();
  return r;  // total valid in thread 0
}

// ---------------- prep stage 1: 16-way sliced partial energies --------------
template <int C, int A, int CROP, int TOP>
__device__ void prep_partial_level(const float* __restrict__ grd,
                                   const float* __restrict__ sat,
                                   const float* __restrict__ mask, int b, int k,
                                   float* __restrict__ part, float* sw) {
  // s1: masked grd crop energy (scalar gather; rows are contiguous)
  const float* gb = grd + (size_t)b * C * A * A;
  float s1 = 0.0f;
  constexpr int N1 = C * CROP * CROP;
  for (int idx = k * 256 + (int)threadIdx.x; idx < N1; idx += 4096) {
    int c = idx / (CROP * CROP);
    int r = idx - c * (CROP * CROP);
    int h = r / CROP;
    int w = r - h * CROP;
    float m = mask[(TOP + h) * A + (TOP + w)];
    float g = gb[((size_t)c * A + (TOP + h)) * A + (TOP + w)] * m;
    s1 += g * g;
  }
  s1 = block_sum256(s1, sw);
  // s2: masked sat energy, float4-vectorized (A*A is a power of two)
  const float4* sb = (const float4*)(sat + (size_t)b * C * A * A);
  const float4* m4 = (const float4*)mask;
  float s2 = 0.0f;
  constexpr int NV = C * A * A / 4;
  constexpr int MV = A * A / 4;
  for (int v = k * 256 + (int)threadIdx.x; v < NV; v += 4096) {
    float4 sv = sb[v];
    float4 mv = m4[v & (MV - 1)];
    s2 += sv.x * sv.x * mv.x + sv.y * sv.y * mv.y + sv.z * sv.z * mv.z +
          sv.w * sv.w * mv.w;
  }
  s2 = block_sum256(s2, sw);
  if (threadIdx.x == 0) {
    part[0] = s1;
    part[1] = s2;
  }
}

__global__ __launch_bounds__(256) void prep_partial_kernel(
    const float* g0, const float* s0, const float* m0, const float* g1,
    const float* s1, const float* m1, const float* g2, const float* s2,
    const float* m2, const float* g3, const float* s3, const float* m3,
    float* ws) {
  __shared__ float sw[4];
  const int pair = blockIdx.x >> 4;   // 0..31
  const int k = blockIdx.x & 15;      // slice 0..15
  const int lev = pair >> 3;
  const int b = pair & 7;
  float* part = ws + WS_PART + (pair * 16 + k) * 2;
  if (lev == 0)      prep_partial_level<64, 16, 6, 5>(g0, s0, m0, b, k, part, sw);
  else if (lev == 1) prep_partial_level<32, 32, 13, 10>(g1, s1, m1, b, k, part, sw);
  else if (lev == 2) prep_partial_level<16, 64, 26, 19>(g2, s2, m2, b, k, part, sw);
  else               prep_partial_level<8, 128, 53, 38>(g3, s3, m3, b, k, part, sw);
}

// ---------------- prep stage 2: finalize scale factors ----------------------
__global__ __launch_bounds__(64) void prep_final_kernel(float* __restrict__ ws,
                                                        float* __restrict__ out) {
  const int t = threadIdx.x;
  if (t == 0) out[0] = 0.0f;  // loss accumulates via atomicAdd; zero each call
  if (t < 32) {
    float s1 = 0.0f, s2 = 0.0f;
    const float* p = ws + WS_PART + t * 32;
    for (int k = 0; k < 16; ++k) {
      s1 += p[2 * k];
      s2 += p[2 * k + 1];
    }
    float norm = sqrtf(s1);
    float denom = fmaxf(sqrtf(s2 + 1e-8f), 1e-6f);
    ws[WS_SC + t] = 2.0f / (fmaxf(norm, 1e-12f) * denom);
  }
}

// ---------------- corr: raw correlation partials ----------------------------
// Per-thread 4-wide sliding window: 4 FMA per 1 new sat load + 1 LDS broadcast.
template <int CROP>
__device__ __forceinline__ void dot_row(const float* __restrict__ srow,
                                        const float* __restrict__ grow,
                                        float acc[4]) {
  float r[4];
  r[0] = srow[0];
  r[1] = srow[1];
  r[2] = srow[2];
#pragma unroll
  for (int w = 0; w < CROP; ++w) {
    r[(w + 3) & 3] = srow[w + 3];  // in-bounds: j0c+CROP+2 <= A-1 by construction
    float g = grow[w];
    acc[0] = fmaf(r[(w + 0) & 3], g, acc[0]);
    acc[1] = fmaf(r[(w + 1) & 3], g, acc[1]);
    acc[2] = fmaf(r[(w + 2) & 3], g, acc[2]);
    acc[3] = fmaf(r[(w + 3) & 3], g, acc[3]);
  }
}

template <int C, int A, int CROP, int TOP, int OH, int NSJ, int SPLITS, int BPB,
          int EBASE>
__device__ void corr_level(int rel, const float* __restrict__ grd,
                           const float* __restrict__ sat,
                           const float* __restrict__ mask,
                           float* __restrict__ ws, float* g_lds) {
  constexpr int CSP = C / SPLITS;
  constexpr int NS = NSJ * OH;
  constexpr int OW = OH;
  constexpr int E = 8 * OH * OW;
  const int perb = SPLITS * BPB;
  const int b = rel / perb;
  const int r2 = rel - b * perb;
  const int split = r2 / BPB;
  const int chunk = r2 - split * BPB;
  const int c0 = split * CSP;

  // stage masked grd chunk into LDS (~11 KB for every level)
  const float* gb = grd + (size_t)(b * C + c0) * A * A;
  constexpr int GN = CSP * CROP * CROP;
  for (int idx = threadIdx.x; idx < GN; idx += 64) {
    int c = idx / (CROP * CROP);
    int r = idx - c * (CROP * CROP);
    int h = r / CROP;
    int w = r - h * CROP;
    g_lds[idx] = gb[((size_t)c * A + (TOP + h)) * A + (TOP + w)] *
                 mask[(TOP + h) * A + (TOP + w)];
  }
  __syncthreads();

  const int s = chunk * 64 + (int)threadIdx.x;
  const bool active = s < NS;
  const int ss = active ? s : 0;
  const int i = ss / NSJ;
  const int j0 = (ss - i * NSJ) * 4;
  const int j0c = min(j0, OW - 4);  // clamp: edge strips overlap, ownership below

  float acc[4] = {0.f, 0.f, 0.f, 0.f};
  const float* sb = sat + (size_t)(b * C + c0) * A * A;
#pragma unroll 1
  for (int c = 0; c < CSP; ++c) {
    const float* satc = sb + (size_t)c * A * A;
    const float* gl = g_lds + c * CROP * CROP;
#pragma unroll 1
    for (int h = 0; h < CROP; ++h) {
      dot_row<CROP>(satc + (i + h) * A + j0c, gl + h * CROP, acc);
    }
  }
  if (active) {
    float* dst = ws + WS_CORR + EBASE + split * E + (b * OH + i) * OW + j0c;
    const int own = j0 - j0c;  // first owned lane of the (possibly clamped) strip
#pragma unroll
    for (int t = 0; t < 4; ++t)
      if (t >= own) dst[t] = acc[t];
  }
}

__global__ __launch_bounds__(64) void corr_kernel(
    const float* g0, const float* s0, const float* m0, const float* g1,
    const float* s1, const float* m1, const float* g2, const float* s2,
    const float* m2, const float* g3, const float* s3, const float* m3,
    float* ws) {
  __shared__ float g_lds[2816];
  const int bid = blockIdx.x;
  if (bid < 8)
    corr_level<64, 16, 6, 5, 11, 3, 1, 1, 0>(bid, g0, s0, m0, ws, g_lds);
  else if (bid < 40)
    corr_level<32, 32, 13, 10, 20, 5, 2, 2, 968>(bid - 8, g1, s1, m1, ws, g_lds);
  else if (bid < 264)
    corr_level<16, 64, 26, 19, 39, 10, 4, 7, 7368>(bid - 40, g2, s2, m2, ws, g_lds);
  else
    corr_level<8, 128, 53, 38, 76, 19, 8, 23, 56040>(bid - 264, g3, s3, m3, ws, g_lds);
}

// ---------------- loss: softplus contrast + scalar reduction ----------------
__global__ __launch_bounds__(256) void loss_kernel(const float* __restrict__ u,
                                                   const float* __restrict__ v,
                                                   const float* __restrict__ hd,
                                                   const float* __restrict__ ws,
                                                   float* __restrict__ out) {
  __shared__ float sw[4];
  const int e = blockIdx.x * 256 + threadIdx.x;
  float term = 0.0f;
  if (e < 62544) {
    int lev, start, OH, EBASE, SPLITS;
    float mpp;
    if (e < 968)        { lev = 0; start = 0;     OH = 11; EBASE = 0;     SPLITS = 1; mpp = 6.4f; }
    else if (e < 4168)  { lev = 1; start = 968;   OH = 20; EBASE = 968;   SPLITS = 2; mpp = 3.2f; }
    else if (e < 16336) { lev = 2; start = 4168;  OH = 39; EBASE = 7368;  SPLITS = 4; mpp = 1.6f; }
    else                { lev = 3; start = 16336; OH = 76; EBASE = 56040; SPLITS = 8; mpp = 0.8f; }
    const int r = e - start;
    const int ow2 = OH * OH;
    const int b = r / ow2;
    const float scv = ws[WS_SC + lev * 8 + b];
    // gt position, replicating the reference fp32 op order
    float t = hd[b] * 10.0f;
    t = t / 180.0f;
    t = t * 3.14159265358979323846f;
    const float cs = cosf(t), sn = sinf(t);
    const float gdx = -u[b] * 20.0f;
    const float gdy = -v[b] * 20.0f;
    const float dxr = -gdx * cs + gdy * sn;
    const float dyr = gdx * sn + gdy * cs;
    int wi = (int)rintf(OH * 0.5f - 0.5f + dxr / mpp);  // rintf = round-half-even
    int hi = (int)rintf(OH * 0.5f - 0.5f + dyr / mpp);
    wi = min(max(wi, 0), OH - 1);
    hi = min(max(hi, 0), OH - 1);
    const int posoff = (b * OH + hi) * OH + wi;
    const int E = 8 * ow2;
    float raw = 0.0f, rp = 0.0f;
    const float* base = ws + WS_CORR + EBASE;
    for (int sp = 0; sp < SPLITS; ++sp) {
      raw += base[sp * E + r];
      rp += base[sp * E + posoff];
    }
    // pos - corr = sc * (raw_entry - raw_pos);  logaddexp(0, 10*(pos-corr))
    const float z = 10.0f * scv * (raw - rp);
    const float spl = fmaxf(z, 0.0f) + log1pf(expf(-fabsf(z)));
    term = spl / (8.0f * (float)(ow2 - 1));
  }
  const float tot = block_sum256(term, sw);
  if (threadIdx.x == 0) atomicAdd(out, tot);
}

// ---------------------------------------------------------------------------
extern "C" void kernel_launch(void* const* d_in, const int* in_sizes, int n_in,
                              void* d_out, int out_size, void* d_ws,
                              size_t ws_size, hipStream_t stream) {
  const float* g0 = (const float*)d_in[0];
  const float* s0 = (const float*)d_in[1];
  const float* m0 = (const float*)d_in[2];
  const float* g1 = (const float*)d_in[3];
  const float* s1 = (const float*)d_in[4];
  const float* m1 = (const float*)d_in[5];
  const float* g2 = (const float*)d_in[6];
  const float* s2 = (const float*)d_in[7];
  const float* m2 = (const float*)d_in[8];
  const float* g3 = (const float*)d_in[9];
  const float* s3 = (const float*)d_in[10];
  const float* m3 = (const float*)d_in[11];
  const float* u  = (const float*)d_in[12];
  const float* v  = (const float*)d_in[13];
  const float* hd = (const float*)d_in[14];
  float* ws = (float*)d_ws;
  float* out = (float*)d_out;

  prep_partial_kernel<<<dim3(512), dim3(256), 0, stream>>>(
      g0, s0, m0, g1, s1, m1, g2, s2, m2, g3, s3, m3, ws);
  prep_final_kernel<<<dim3(1), dim3(64), 0, stream>>>(ws, out);
  corr_kernel<<<dim3(1736), dim3(64), 0, stream>>>(g0, s0, m0, g1, s1, m1, g2,
                                                   s2, m2, g3, s3, m3, ws);
  loss_kernel<<<dim3(245), dim3(256), 0, stream>>>(u, v, hd, ws, out);
}

// Round 5
// 152.711 us; speedup vs baseline: 2.0357x; 1.1871x over previous
//
#include <hip/hip_runtime.h>
#include <math.h>

// ---------------------------------------------------------------------------
// MutilLocalLoss on MI355X.
// Level constants (match Python int()/round() semantics exactly):
//   lev: C,  A,  CROP, TOP, OH(=OW), NSJ, NS,  CSPLIT, RSPLIT, CHUNKS, START
//   0:   64, 16,  6,    5,  11,      3,   33,  4,      1,      1,      0
//   1:   32, 32, 13,   10,  20,      5,  100,  2,      4,      2,      968
//   2:   16, 64, 26,   19,  39,     10,  390,  4,      4,      7,      4168
//   3:    8,128, 53,   38,  76,     19, 1444,  8,      4,     23,      16336
// R3: prep was 266µs latency-bound -> split/vectorized (311->181µs).
// R4: corr was 174µs latency-bound (1.1 waves/SIMD, VALUBusy 15%). Fix:
//     channel+filter-row split -> 6944 waves (6.8/SIMD), atomicAdd into ONE
//     compact 62544-float corr buffer (no ws growth), unroll-2 row loop.
// ws floats: [0,32) sc; [32, 32+62544) corr accum; [62576, +1024) prep parts.
// ---------------------------------------------------------------------------

#define WS_SC 0
#define WS_CORR 32
#define WS_PART (32 + 62544)
#define N_ENTRIES 62544

__device__ __forceinline__ float block_sum256(float v, float* sw) {
#pragma unroll
  for (int o = 32; o > 0; o >>= 1) v += __shfl_down(v, o, 64);
  if ((threadIdx.x & 63) == 0) sw[threadIdx.x >> 6] = v;
  __syncthreads();
  float r = (threadIdx.x < 4) ? sw[threadIdx.x] : 0.0f;
  r += __shfl_down(r, 2, 64);
  r += __shfl_down(r, 1, 64);
  __syncthreads();
  return r;  // total valid in thread 0
}

// ---------------- init: zero corr accumulators + out ------------------------
__global__ __launch_bounds__(256) void init_kernel(float* __restrict__ ws,
                                                   float* __restrict__ out) {
  const int e = blockIdx.x * 256 + threadIdx.x;
  if (e < N_ENTRIES) ws[WS_CORR + e] = 0.0f;
  if (e == 0) out[0] = 0.0f;
}

// ---------------- prep stage 1: 16-way sliced partial energies --------------
template <int C, int A, int CROP, int TOP>
__device__ void prep_partial_level(const float* __restrict__ grd,
                                   const float* __restrict__ sat,
                                   const float* __restrict__ mask, int b, int k,
                                   float* __restrict__ part, float* sw) {
  const float* gb = grd + (size_t)b * C * A * A;
  float s1 = 0.0f;
  constexpr int N1 = C * CROP * CROP;
  for (int idx = k * 256 + (int)threadIdx.x; idx < N1; idx += 4096) {
    int c = idx / (CROP * CROP);
    int r = idx - c * (CROP * CROP);
    int h = r / CROP;
    int w = r - h * CROP;
    float m = mask[(TOP + h) * A + (TOP + w)];
    float g = gb[((size_t)c * A + (TOP + h)) * A + (TOP + w)] * m;
    s1 += g * g;
  }
  s1 = block_sum256(s1, sw);
  const float4* sb = (const float4*)(sat + (size_t)b * C * A * A);
  const float4* m4 = (const float4*)mask;
  float s2 = 0.0f;
  constexpr int NV = C * A * A / 4;
  constexpr int MV = A * A / 4;
  for (int v = k * 256 + (int)threadIdx.x; v < NV; v += 4096) {
    float4 sv = sb[v];
    float4 mv = m4[v & (MV - 1)];
    s2 += sv.x * sv.x * mv.x + sv.y * sv.y * mv.y + sv.z * sv.z * mv.z +
          sv.w * sv.w * mv.w;
  }
  s2 = block_sum256(s2, sw);
  if (threadIdx.x == 0) {
    part[0] = s1;
    part[1] = s2;
  }
}

__global__ __launch_bounds__(256) void prep_partial_kernel(
    const float* g0, const float* s0, const float* m0, const float* g1,
    const float* s1, const float* m1, const float* g2, const float* s2,
    const float* m2, const float* g3, const float* s3, const float* m3,
    float* ws) {
  __shared__ float sw[4];
  const int pair = blockIdx.x >> 4;   // 0..31
  const int k = blockIdx.x & 15;      // slice 0..15
  const int lev = pair >> 3;
  const int b = pair & 7;
  float* part = ws + WS_PART + (pair * 16 + k) * 2;
  if (lev == 0)      prep_partial_level<64, 16, 6, 5>(g0, s0, m0, b, k, part, sw);
  else if (lev == 1) prep_partial_level<32, 32, 13, 10>(g1, s1, m1, b, k, part, sw);
  else if (lev == 2) prep_partial_level<16, 64, 26, 19>(g2, s2, m2, b, k, part, sw);
  else               prep_partial_level<8, 128, 53, 38>(g3, s3, m3, b, k, part, sw);
}

// ---------------- prep stage 2: finalize scale factors ----------------------
__global__ __launch_bounds__(64) void prep_final_kernel(float* __restrict__ ws) {
  const int t = threadIdx.x;
  if (t < 32) {
    float s1 = 0.0f, s2 = 0.0f;
    const float* p = ws + WS_PART + t * 32;
    for (int k = 0; k < 16; ++k) {
      s1 += p[2 * k];
      s2 += p[2 * k + 1];
    }
    float norm = sqrtf(s1);
    float denom = fmaxf(sqrtf(s2 + 1e-8f), 1e-6f);
    ws[WS_SC + t] = 2.0f / (fmaxf(norm, 1e-12f) * denom);
  }
}

// ---------------- corr: raw correlation partials (atomic accumulate) --------
// Per-thread 4-wide sliding window: 4 FMA per 1 new sat load + 1 LDS broadcast.
template <int CROP>
__device__ __forceinline__ void dot_row(const float* __restrict__ srow,
                                        const float* __restrict__ grow,
                                        float acc[4]) {
  float r[4];
  r[0] = srow[0];
  r[1] = srow[1];
  r[2] = srow[2];
#pragma unroll
  for (int w = 0; w < CROP; ++w) {
    r[(w + 3) & 3] = srow[w + 3];  // in-bounds: j0c+CROP+2 <= A-1 by construction
    float g = grow[w];
    acc[0] = fmaf(r[(w + 0) & 3], g, acc[0]);
    acc[1] = fmaf(r[(w + 1) & 3], g, acc[1]);
    acc[2] = fmaf(r[(w + 2) & 3], g, acc[2]);
    acc[3] = fmaf(r[(w + 3) & 3], g, acc[3]);
  }
}

template <int C, int A, int CROP, int TOP, int OH, int NSJ, int CSPLIT,
          int RSPLIT, int CHUNKS, int START>
__device__ void corr_level(int rel, const float* __restrict__ grd,
                           const float* __restrict__ sat,
                           const float* __restrict__ mask,
                           float* __restrict__ ws, float* g_lds) {
  constexpr int CSP = C / CSPLIT;
  constexpr int NS = NSJ * OH;
  constexpr int OW = OH;
  constexpr int perb = CSPLIT * RSPLIT * CHUNKS;
  const int b = rel / perb;
  int r2 = rel - b * perb;
  const int cs = r2 / (RSPLIT * CHUNKS);
  r2 -= cs * (RSPLIT * CHUNKS);
  const int rs = r2 / CHUNKS;
  const int chunk = r2 - rs * CHUNKS;
  const int c0 = cs * CSP;
  const int r0 = (rs * CROP) / RSPLIT;       // filter-row slice [r0, r1)
  const int r1 = ((rs + 1) * CROP) / RSPLIT;
  const int nr = r1 - r0;

  // stage masked grd row-slice into LDS (<= 832 floats)
  const float* gb = grd + (size_t)(b * C + c0) * A * A;
  const int GN = CSP * nr * CROP;
  for (int idx = threadIdx.x; idx < GN; idx += 64) {
    int c = idx / (nr * CROP);
    int rem = idx - c * (nr * CROP);
    int h = rem / CROP;
    int w = rem - h * CROP;
    g_lds[idx] = gb[((size_t)c * A + (TOP + r0 + h)) * A + (TOP + w)] *
                 mask[(TOP + r0 + h) * A + (TOP + w)];
  }
  __syncthreads();

  const int s = chunk * 64 + (int)threadIdx.x;
  const bool active = s < NS;
  const int ss = active ? s : 0;
  const int i = ss / NSJ;
  const int j0 = (ss - i * NSJ) * 4;
  const int j0c = min(j0, OW - 4);  // clamp: edge strips overlap, ownership below

  float acc[4] = {0.f, 0.f, 0.f, 0.f};
  const float* sb = sat + (size_t)(b * C + c0) * A * A;
#pragma unroll 1
  for (int c = 0; c < CSP; ++c) {
    const float* satc = sb + (size_t)c * A * A + (size_t)(i + r0) * A + j0c;
    const float* gl = g_lds + c * nr * CROP;
#pragma unroll 2
    for (int h = 0; h < nr; ++h) {
      dot_row<CROP>(satc + h * A, gl + h * CROP, acc);
    }
  }
  if (active) {
    float* dst = ws + WS_CORR + START + (b * OH + i) * OW + j0c;
    const int own = j0 - j0c;  // first owned lane of the (possibly clamped) strip
#pragma unroll
    for (int t = 0; t < 4; ++t)
      if (t >= own) atomicAdd(dst + t, acc[t]);
  }
}

__global__ __launch_bounds__(64) void corr_kernel(
    const float* g0, const float* s0, const float* m0, const float* g1,
    const float* s1, const float* m1, const float* g2, const float* s2,
    const float* m2, const float* g3, const float* s3, const float* m3,
    float* ws) {
  __shared__ float g_lds[896];
  const int bid = blockIdx.x;
  if (bid < 32)
    corr_level<64, 16, 6, 5, 11, 3, 4, 1, 1, 0>(bid, g0, s0, m0, ws, g_lds);
  else if (bid < 160)
    corr_level<32, 32, 13, 10, 20, 5, 2, 4, 2, 968>(bid - 32, g1, s1, m1, ws, g_lds);
  else if (bid < 1056)
    corr_level<16, 64, 26, 19, 39, 10, 4, 4, 7, 4168>(bid - 160, g2, s2, m2, ws, g_lds);
  else
    corr_level<8, 128, 53, 38, 76, 19, 8, 4, 23, 16336>(bid - 1056, g3, s3, m3, ws, g_lds);
}

// ---------------- loss: softplus contrast + scalar reduction ----------------
__global__ __launch_bounds__(256) void loss_kernel(const float* __restrict__ u,
                                                   const float* __restrict__ v,
                                                   const float* __restrict__ hd,
                                                   const float* __restrict__ ws,
                                                   float* __restrict__ out) {
  __shared__ float sw[4];
  const int e = blockIdx.x * 256 + threadIdx.x;
  float term = 0.0f;
  if (e < N_ENTRIES) {
    int lev, start, OH;
    float mpp;
    if (e < 968)        { lev = 0; start = 0;     OH = 11; mpp = 6.4f; }
    else if (e < 4168)  { lev = 1; start = 968;   OH = 20; mpp = 3.2f; }
    else if (e < 16336) { lev = 2; start = 4168;  OH = 39; mpp = 1.6f; }
    else                { lev = 3; start = 16336; OH = 76; mpp = 0.8f; }
    const int r = e - start;
    const int ow2 = OH * OH;
    const int b = r / ow2;
    const float scv = ws[WS_SC + lev * 8 + b];
    // gt position, replicating the reference fp32 op order
    float t = hd[b] * 10.0f;
    t = t / 180.0f;
    t = t * 3.14159265358979323846f;
    const float cs = cosf(t), sn = sinf(t);
    const float gdx = -u[b] * 20.0f;
    const float gdy = -v[b] * 20.0f;
    const float dxr = -gdx * cs + gdy * sn;
    const float dyr = gdx * sn + gdy * cs;
    int wi = (int)rintf(OH * 0.5f - 0.5f + dxr / mpp);  // rintf = round-half-even
    int hi = (int)rintf(OH * 0.5f - 0.5f + dyr / mpp);
    wi = min(max(wi, 0), OH - 1);
    hi = min(max(hi, 0), OH - 1);
    const float raw = ws[WS_CORR + e];
    const float rp = ws[WS_CORR + start + (b * OH + hi) * OH + wi];
    // pos - corr = sc * (raw_entry - raw_pos);  logaddexp(0, 10*(pos-corr))
    const float z = 10.0f * scv * (raw - rp);
    const float spl = fmaxf(z, 0.0f) + log1pf(expf(-fabsf(z)));
    term = spl / (8.0f * (float)(ow2 - 1));
  }
  const float tot = block_sum256(term, sw);
  if (threadIdx.x == 0) atomicAdd(out, tot);
}

// ---------------------------------------------------------------------------
extern "C" void kernel_launch(void* const* d_in, const int* in_sizes, int n_in,
                              void* d_out, int out_size, void* d_ws,
                              size_t ws_size, hipStream_t stream) {
  const float* g0 = (const float*)d_in[0];
  const float* s0 = (const float*)d_in[1];
  const float* m0 = (const float*)d_in[2];
  const float* g1 = (const float*)d_in[3];
  const float* s1 = (const float*)d_in[4];
  const float* m1 = (const float*)d_in[5];
  const float* g2 = (const float*)d_in[6];
  const float* s2 = (const float*)d_in[7];
  const float* m2 = (const float*)d_in[8];
  const float* g3 = (const float*)d_in[9];
  const float* s3 = (const float*)d_in[10];
  const float* m3 = (const float*)d_in[11];
  const float* u  = (const float*)d_in[12];
  const float* v  = (const float*)d_in[13];
  const float* hd = (const float*)d_in[14];
  float* ws = (float*)d_ws;
  float* out = (float*)d_out;

  init_kernel<<<dim3(245), dim3(256), 0, stream>>>(ws, out);
  prep_partial_kernel<<<dim3(512), dim3(256), 0, stream>>>(
      g0, s0, m0, g1, s1, m1, g2, s2, m2, g3, s3, m3, ws);
  prep_final_kernel<<<dim3(1), dim3(64), 0, stream>>>(ws);
  corr_kernel<<<dim3(6944), dim3(64), 0, stream>>>(g0, s0, m0, g1, s1, m1, g2,
                                                   s2, m2, g3, s3, m3, ws);
  loss_kernel<<<dim3(245), dim3(256), 0, stream>>>(u, v, hd, ws, out);
}

// Round 6
// 150.484 us; speedup vs baseline: 2.0658x; 1.0148x over previous
//
#include <hip/hip_runtime.h>
#include <math.h>

// ---------------------------------------------------------------------------
// MutilLocalLoss on MI355X.
// Level constants (match Python int()/round() semantics exactly):
//   lev: C,  A,  CROP, TOP, OH(=OW), NSJ, NS,  CSPLIT, RSPLIT, CHUNKS, START
//   0:   64, 16,  6,    5,  11,      3,   33,  4,      1,      1,      0
//   1:   32, 32, 13,   10,  20,      5,  100,  2,      4,      2,      968
//   2:   16, 64, 26,   19,  39,     10,  390,  4,      4,      7,      4168
//   3:    8,128, 53,   38,  76,     19, 1444,  8,      4,     23,      16336
// R3: prep 266µs latency-bound -> split/vectorized (311->181µs).
// R4: corr 174µs latency-bound (1.1 waves/SIMD) -> 6944 waves + atomics (153µs).
// R5: corr 144µs STILL latency-bound in-wave (VALUBusy 24%): sliding-window
//     scalar loads = 1 dependent load per 4 FMA, ~2 in flight. Fix: float4
//     row buffer in registers (independent loads, static indices), strips
//     always 4-aligned (no position clamp); tail handled by store mask +
//     clamping only the LAST float4 address (uniform code, no divergence).
//     Safety proof per level: valid accs only read rbuf[w+t] with
//     w+t <= CROP-1 + (OW-1-j0), which lies in the unclamped region whenever
//     the last-load clamp is active (checked for all 4 levels).
// ws floats: [0,32) sc; [32, 32+62544) corr accum; [62576, +1024) prep parts.
// ---------------------------------------------------------------------------

#define WS_SC 0
#define WS_CORR 32
#define WS_PART (32 + 62544)
#define N_ENTRIES 62544

__device__ __forceinline__ float block_sum256(float v, float* sw) {
#pragma unroll
  for (int o = 32; o > 0; o >>= 1) v += __shfl_down(v, o, 64);
  if ((threadIdx.x & 63) == 0) sw[threadIdx.x >> 6] = v;
  __syncthreads();
  float r = (threadIdx.x < 4) ? sw[threadIdx.x] : 0.0f;
  r += __shfl_down(r, 2, 64);
  r += __shfl_down(r, 1, 64);
  __syncthreads();
  return r;  // total valid in thread 0
}

// ---------------- init: zero corr accumulators + out ------------------------
__global__ __launch_bounds__(256) void init_kernel(float* __restrict__ ws,
                                                   float* __restrict__ out) {
  const int e = blockIdx.x * 256 + threadIdx.x;
  if (e < N_ENTRIES) ws[WS_CORR + e] = 0.0f;
  if (e == 0) out[0] = 0.0f;
}

// ---------------- prep stage 1: 16-way sliced partial energies --------------
template <int C, int A, int CROP, int TOP>
__device__ void prep_partial_level(const float* __restrict__ grd,
                                   const float* __restrict__ sat,
                                   const float* __restrict__ mask, int b, int k,
                                   float* __restrict__ part, float* sw) {
  const float* gb = grd + (size_t)b * C * A * A;
  float s1 = 0.0f;
  constexpr int N1 = C * CROP * CROP;
  for (int idx = k * 256 + (int)threadIdx.x; idx < N1; idx += 4096) {
    int c = idx / (CROP * CROP);
    int r = idx - c * (CROP * CROP);
    int h = r / CROP;
    int w = r - h * CROP;
    float m = mask[(TOP + h) * A + (TOP + w)];
    float g = gb[((size_t)c * A + (TOP + h)) * A + (TOP + w)] * m;
    s1 += g * g;
  }
  s1 = block_sum256(s1, sw);
  const float4* sb = (const float4*)(sat + (size_t)b * C * A * A);
  const float4* m4 = (const float4*)mask;
  float s2 = 0.0f;
  constexpr int NV = C * A * A / 4;
  constexpr int MV = A * A / 4;
  for (int v = k * 256 + (int)threadIdx.x; v < NV; v += 4096) {
    float4 sv = sb[v];
    float4 mv = m4[v & (MV - 1)];
    s2 += sv.x * sv.x * mv.x + sv.y * sv.y * mv.y + sv.z * sv.z * mv.z +
          sv.w * sv.w * mv.w;
  }
  s2 = block_sum256(s2, sw);
  if (threadIdx.x == 0) {
    part[0] = s1;
    part[1] = s2;
  }
}

__global__ __launch_bounds__(256) void prep_partial_kernel(
    const float* g0, const float* s0, const float* m0, const float* g1,
    const float* s1, const float* m1, const float* g2, const float* s2,
    const float* m2, const float* g3, const float* s3, const float* m3,
    float* ws) {
  __shared__ float sw[4];
  const int pair = blockIdx.x >> 4;   // 0..31
  const int k = blockIdx.x & 15;      // slice 0..15
  const int lev = pair >> 3;
  const int b = pair & 7;
  float* part = ws + WS_PART + (pair * 16 + k) * 2;
  if (lev == 0)      prep_partial_level<64, 16, 6, 5>(g0, s0, m0, b, k, part, sw);
  else if (lev == 1) prep_partial_level<32, 32, 13, 10>(g1, s1, m1, b, k, part, sw);
  else if (lev == 2) prep_partial_level<16, 64, 26, 19>(g2, s2, m2, b, k, part, sw);
  else               prep_partial_level<8, 128, 53, 38>(g3, s3, m3, b, k, part, sw);
}

// ---------------- prep stage 2: finalize scale factors ----------------------
__global__ __launch_bounds__(64) void prep_final_kernel(float* __restrict__ ws) {
  const int t = threadIdx.x;
  if (t < 32) {
    float s1 = 0.0f, s2 = 0.0f;
    const float* p = ws + WS_PART + t * 32;
    for (int k = 0; k < 16; ++k) {
      s1 += p[2 * k];
      s2 += p[2 * k + 1];
    }
    float norm = sqrtf(s1);
    float denom = fmaxf(sqrtf(s2 + 1e-8f), 1e-6f);
    ws[WS_SC + t] = 2.0f / (fmaxf(norm, 1e-12f) * denom);
  }
}

// ---------------- corr: raw correlation partials (atomic accumulate) --------
// Row kernel: load the thread's sat row span as float4s into a fully-static
// register buffer (independent loads -> deep MLP), then 4-output FMA sweep.
template <int CROP, int NV4>
__device__ __forceinline__ void dot_row_vec(const float* __restrict__ srow,
                                            int lastoff,
                                            const float* __restrict__ grow,
                                            float acc[4]) {
  float rbuf[NV4 * 4];
#pragma unroll
  for (int k = 0; k < NV4 - 1; ++k) {
    float4 t = *(const float4*)(srow + 4 * k);
    rbuf[4 * k + 0] = t.x;
    rbuf[4 * k + 1] = t.y;
    rbuf[4 * k + 2] = t.z;
    rbuf[4 * k + 3] = t.w;
  }
  {
    float4 t = *(const float4*)(srow + lastoff);  // clamped: may duplicate
    rbuf[4 * (NV4 - 1) + 0] = t.x;
    rbuf[4 * (NV4 - 1) + 1] = t.y;
    rbuf[4 * (NV4 - 1) + 2] = t.z;
    rbuf[4 * (NV4 - 1) + 3] = t.w;
  }
#pragma unroll
  for (int w = 0; w < CROP; ++w) {
    const float g = grow[w];
    acc[0] = fmaf(rbuf[w + 0], g, acc[0]);
    acc[1] = fmaf(rbuf[w + 1], g, acc[1]);
    acc[2] = fmaf(rbuf[w + 2], g, acc[2]);
    acc[3] = fmaf(rbuf[w + 3], g, acc[3]);
  }
}

template <int C, int A, int CROP, int TOP, int OH, int NSJ, int CSPLIT,
          int RSPLIT, int CHUNKS, int START>
__device__ void corr_level(int rel, const float* __restrict__ grd,
                           const float* __restrict__ sat,
                           const float* __restrict__ mask,
                           float* __restrict__ ws, float* g_lds) {
  constexpr int CSP = C / CSPLIT;
  constexpr int NS = NSJ * OH;
  constexpr int OW = OH;
  constexpr int NV4 = (CROP + 3 + 3) / 4;  // ceil((CROP+3)/4) float4 per row
  constexpr int perb = CSPLIT * RSPLIT * CHUNKS;
  const int b = rel / perb;
  int r2 = rel - b * perb;
  const int cs = r2 / (RSPLIT * CHUNKS);
  r2 -= cs * (RSPLIT * CHUNKS);
  const int rs = r2 / CHUNKS;
  const int chunk = r2 - rs * CHUNKS;
  const int c0 = cs * CSP;
  const int r0 = (rs * CROP) / RSPLIT;       // filter-row slice [r0, r1)
  const int r1 = ((rs + 1) * CROP) / RSPLIT;
  const int nr = r1 - r0;

  // stage masked grd row-slice into LDS (<= 832 floats)
  const float* gb = grd + (size_t)(b * C + c0) * A * A;
  const int GN = CSP * nr * CROP;
  for (int idx = threadIdx.x; idx < GN; idx += 64) {
    int c = idx / (nr * CROP);
    int rem = idx - c * (nr * CROP);
    int h = rem / CROP;
    int w = rem - h * CROP;
    g_lds[idx] = gb[((size_t)c * A + (TOP + r0 + h)) * A + (TOP + w)] *
                 mask[(TOP + r0 + h) * A + (TOP + w)];
  }
  __syncthreads();

  const int s = chunk * 64 + (int)threadIdx.x;
  const bool active = s < NS;
  const int ss = active ? s : 0;
  const int i = ss / NSJ;
  const int j0 = (ss - i * NSJ) * 4;            // always 16B-aligned
  const int lastoff = min(4 * (NV4 - 1), A - 4 - j0);  // clamp final float4

  float acc[4] = {0.f, 0.f, 0.f, 0.f};
  const float* sb =
      sat + (size_t)(b * C + c0) * A * A + (size_t)(i + r0) * A + j0;
#pragma unroll 1
  for (int c = 0; c < CSP; ++c) {
    const float* satc = sb + (size_t)c * A * A;
    const float* gl = g_lds + c * nr * CROP;
#pragma unroll 1
    for (int h = 0; h < nr; ++h) {
      dot_row_vec<CROP, NV4>(satc + h * A, lastoff, gl + h * CROP, acc);
    }
  }
  if (active) {
    float* dst = ws + WS_CORR + START + (b * OH + i) * OW + j0;
#pragma unroll
    for (int t = 0; t < 4; ++t)
      if (j0 + t < OW) atomicAdd(dst + t, acc[t]);
  }
}

__global__ __launch_bounds__(64) void corr_kernel(
    const float* g0, const float* s0, const float* m0, const float* g1,
    const float* s1, const float* m1, const float* g2, const float* s2,
    const float* m2, const float* g3, const float* s3, const float* m3,
    float* ws) {
  __shared__ float g_lds[896];
  const int bid = blockIdx.x;
  if (bid < 32)
    corr_level<64, 16, 6, 5, 11, 3, 4, 1, 1, 0>(bid, g0, s0, m0, ws, g_lds);
  else if (bid < 160)
    corr_level<32, 32, 13, 10, 20, 5, 2, 4, 2, 968>(bid - 32, g1, s1, m1, ws, g_lds);
  else if (bid < 1056)
    corr_level<16, 64, 26, 19, 39, 10, 4, 4, 7, 4168>(bid - 160, g2, s2, m2, ws, g_lds);
  else
    corr_level<8, 128, 53, 38, 76, 19, 8, 4, 23, 16336>(bid - 1056, g3, s3, m3, ws, g_lds);
}

// ---------------- loss: softplus contrast + scalar reduction ----------------
__global__ __launch_bounds__(256) void loss_kernel(const float* __restrict__ u,
                                                   const float* __restrict__ v,
                                                   const float* __restrict__ hd,
                                                   const float* __restrict__ ws,
                                                   float* __restrict__ out) {
  __shared__ float sw[4];
  const int e = blockIdx.x * 256 + threadIdx.x;
  float term = 0.0f;
  if (e < N_ENTRIES) {
    int lev, start, OH;
    float mpp;
    if (e < 968)        { lev = 0; start = 0;     OH = 11; mpp = 6.4f; }
    else if (e < 4168)  { lev = 1; start = 968;   OH = 20; mpp = 3.2f; }
    else if (e < 16336) { lev = 2; start = 4168;  OH = 39; mpp = 1.6f; }
    else                { lev = 3; start = 16336; OH = 76; mpp = 0.8f; }
    const int r = e - start;
    const int ow2 = OH * OH;
    const int b = r / ow2;
    const float scv = ws[WS_SC + lev * 8 + b];
    // gt position, replicating the reference fp32 op order
    float t = hd[b] * 10.0f;
    t = t / 180.0f;
    t = t * 3.14159265358979323846f;
    const float cs = cosf(t), sn = sinf(t);
    const float gdx = -u[b] * 20.0f;
    const float gdy = -v[b] * 20.0f;
    const float dxr = -gdx * cs + gdy * sn;
    const float dyr = gdx * sn + gdy * cs;
    int wi = (int)rintf(OH * 0.5f - 0.5f + dxr / mpp);  // rintf = round-half-even
    int hi = (int)rintf(OH * 0.5f - 0.5f + dyr / mpp);
    wi = min(max(wi, 0), OH - 1);
    hi = min(max(hi, 0), OH - 1);
    const float raw = ws[WS_CORR + e];
    const float rp = ws[WS_CORR + start + (b * OH + hi) * OH + wi];
    // pos - corr = sc * (raw_entry - raw_pos);  logaddexp(0, 10*(pos-corr))
    const float z = 10.0f * scv * (raw - rp);
    const float spl = fmaxf(z, 0.0f) + log1pf(expf(-fabsf(z)));
    term = spl / (8.0f * (float)(ow2 - 1));
  }
  const float tot = block_sum256(term, sw);
  if (threadIdx.x == 0) atomicAdd(out, tot);
}

// ---------------------------------------------------------------------------
extern "C" void kernel_launch(void* const* d_in, const int* in_sizes, int n_in,
                              void* d_out, int out_size, void* d_ws,
                              size_t ws_size, hipStream_t stream) {
  const float* g0 = (const float*)d_in[0];
  const float* s0 = (const float*)d_in[1];
  const float* m0 = (const float*)d_in[2];
  const float* g1 = (const float*)d_in[3];
  const float* s1 = (const float*)d_in[4];
  const float* m1 = (const float*)d_in[5];
  const float* g2 = (const float*)d_in[6];
  const float* s2 = (const float*)d_in[7];
  const float* m2 = (const float*)d_in[8];
  const float* g3 = (const float*)d_in[9];
  const float* s3 = (const float*)d_in[10];
  const float* m3 = (const float*)d_in[11];
  const float* u  = (const float*)d_in[12];
  const float* v  = (const float*)d_in[13];
  const float* hd = (const float*)d_in[14];
  float* ws = (float*)d_ws;
  float* out = (float*)d_out;

  init_kernel<<<dim3(245), dim3(256), 0, stream>>>(ws, out);
  prep_partial_kernel<<<dim3(512), dim3(256), 0, stream>>>(
      g0, s0, m0, g1, s1, m1, g2, s2, m2, g3, s3, m3, ws);
  prep_final_kernel<<<dim3(1), dim3(64), 0, stream>>>(ws);
  corr_kernel<<<dim3(6944), dim3(64), 0, stream>>>(g0, s0, m0, g1, s1, m1, g2,
                                                   s2, m2, g3, s3, m3, ws);
  loss_kernel<<<dim3(245), dim3(256), 0, stream>>>(u, v, hd, ws, out);
}